// Round 1
// baseline (118.419 us; speedup 1.0000x reference)
//
#include <hip/hip_runtime.h>

#define IN_DIM 128
#define NB 5

// ---------------------------------------------------------------------------
// Kernel 0: compute base_scores[k] = dot(bases[k], scorer_w)  (5 waves)
//           + detect whether edge_index is int64 (stride 2) or int32 (stride 1)
// ---------------------------------------------------------------------------
__global__ __launch_bounds__(384) void prep_kernel(
    const float* __restrict__ bases,      // [5][256]
    const float* __restrict__ scorer_w,   // [256]
    const int*   __restrict__ eidx,       // index buffer viewed as int32
    float* __restrict__ bs,               // out: [5]
    int*   __restrict__ flag)             // out: stride (1 or 2)
{
    int t = threadIdx.x;
    int w = t >> 6, l = t & 63;
    if (w < NB) {
        float p = 0.f;
        #pragma unroll
        for (int c = 0; c < 4; ++c) {
            int d = l + 64 * c;
            p = fmaf(bases[w * 256 + d], scorer_w[d], p);
        }
        #pragma unroll
        for (int off = 32; off > 0; off >>= 1)
            p += __shfl_xor(p, off, 64);
        if (l == 0) bs[w] = p;
    } else if (w == NB && l == 0) {
        // int64 little-endian: high dwords (odd slots) of nonneg small values are 0
        int nz = 0;
        for (int i = 1; i < 128; i += 2) nz |= eidx[i];
        *flag = nz ? 1 : 2;
    }
}

// ---------------------------------------------------------------------------
// Kernel 1: per-node projection table
//   proj[n][0..4]  = x[n] . attn_w[j][0:128]     (src half)
//   proj[n][5]     = x[n] . scorer_w[0:128]
//   proj[n][8..12] = x[n] . attn_w[j][128:256]   (dst half)
//   proj[n][13]    = x[n] . scorer_w[128:256]
// (16 floats/node for aligned float4 access; slots 6,7,14,15 are pad)
// ---------------------------------------------------------------------------
__global__ __launch_bounds__(256) void proj_kernel(
    const float* __restrict__ x,          // [N][128]
    const float* __restrict__ attn_w,     // [5][256]
    const float* __restrict__ scorer_w,   // [256]
    float* __restrict__ proj,             // [N][16]
    int n_nodes)
{
    int n = blockIdx.x * blockDim.x + threadIdx.x;
    if (n >= n_nodes) return;

    const float4* __restrict__ xr = (const float4*)(x + (size_t)n * IN_DIM);

    float acc[12];
    #pragma unroll
    for (int j = 0; j < 12; ++j) acc[j] = 0.f;

    #pragma unroll 4
    for (int q = 0; q < IN_DIM / 4; ++q) {
        float4 v = xr[q];
        #pragma unroll
        for (int j = 0; j < 6; ++j) {
            // weight row: attn_w[j] for j<5, scorer_w for j==5 (wave-uniform addr)
            const float* __restrict__ w = (j < NB) ? (attn_w + j * 256) : scorer_w;
            float4 wa = *(const float4*)(w + q * 4);            // first-half dims
            float4 wb = *(const float4*)(w + IN_DIM + q * 4);   // second-half dims
            acc[j]     = fmaf(v.x, wa.x, fmaf(v.y, wa.y, fmaf(v.z, wa.z, fmaf(v.w, wa.w, acc[j]))));
            acc[6 + j] = fmaf(v.x, wb.x, fmaf(v.y, wb.y, fmaf(v.z, wb.z, fmaf(v.w, wb.w, acc[6 + j]))));
        }
    }

    float4* __restrict__ pr = (float4*)(proj + (size_t)n * 16);
    pr[0] = make_float4(acc[0], acc[1], acc[2],  acc[3]);
    pr[1] = make_float4(acc[4], acc[5], 0.f,     0.f);
    pr[2] = make_float4(acc[6], acc[7], acc[8],  acc[9]);
    pr[3] = make_float4(acc[10], acc[11], 0.f,   0.f);
}

// ---------------------------------------------------------------------------
// Kernel 2: per-edge attention + scorer
// ---------------------------------------------------------------------------
__global__ __launch_bounds__(256) void edge_kernel(
    const int*   __restrict__ eidx,       // int32 view of edge_index
    const float* __restrict__ ew,         // [E]
    const float* __restrict__ attn_b,     // [5]
    const float* __restrict__ scorer_b,   // [1]
    const float* __restrict__ proj,       // [N][16]
    const float* __restrict__ bs,         // [5] base scores
    const int*   __restrict__ flag,       // index stride
    float* __restrict__ out,              // [E]
    int n_edges)
{
    const int stride = *flag;  // wave-uniform
    const float b0 = attn_b[0], b1 = attn_b[1], b2 = attn_b[2],
                b3 = attn_b[3], b4 = attn_b[4];
    const float sb = scorer_b[0];
    const float s0 = bs[0], s1 = bs[1], s2 = bs[2], s3 = bs[3], s4 = bs[4];

    for (int e = blockIdx.x * blockDim.x + threadIdx.x; e < n_edges;
         e += gridDim.x * blockDim.x) {
        int src = eidx[(size_t)e * stride];
        int dst = eidx[((size_t)n_edges + e) * stride];

        const float4* __restrict__ ps = (const float4*)(proj + (size_t)src * 16);
        const float4* __restrict__ pd = (const float4*)(proj + (size_t)dst * 16) + 2;
        float4 a0 = ps[0], a1 = ps[1];   // src half: A0..A5
        float4 c0 = pd[0], c1 = pd[1];   // dst half: B0..B5

        float l0 = a0.x + c0.x + b0;
        float l1 = a0.y + c0.y + b1;
        float l2 = a0.z + c0.z + b2;
        float l3 = a0.w + c0.w + b3;
        float l4 = a1.x + c1.x + b4;
        float lsc = a1.y + c1.y;          // scorer partial (edge_feats . scorer_w)

        // softmax over 5 logits
        float m = fmaxf(fmaxf(fmaxf(l0, l1), fmaxf(l2, l3)), l4);
        float e0 = __expf(l0 - m);
        float e1 = __expf(l1 - m);
        float e2 = __expf(l2 - m);
        float e3 = __expf(l3 - m);
        float e4 = __expf(l4 - m);
        float inv = 1.f / (e0 + e1 + e2 + e3 + e4);

        float mix = (e0 * s0 + e1 * s1 + e2 * s2 + e3 * s3 + e4 * s4) * inv;
        float logit = lsc + mix + sb;
        float sc = 1.f / (1.f + __expf(-logit));
        out[e] = ew[e] * sc;
    }
}

// ---------------------------------------------------------------------------
extern "C" void kernel_launch(void* const* d_in, const int* in_sizes, int n_in,
                              void* d_out, int out_size, void* d_ws, size_t ws_size,
                              hipStream_t stream) {
    const float* x        = (const float*)d_in[0];
    const int*   eidx     = (const int*)  d_in[1];
    const float* ew       = (const float*)d_in[2];
    const float* bases    = (const float*)d_in[3];
    const float* attn_w   = (const float*)d_in[4];
    const float* attn_b   = (const float*)d_in[5];
    const float* scorer_w = (const float*)d_in[6];
    const float* scorer_b = (const float*)d_in[7];
    float* out = (float*)d_out;

    const int n_nodes = in_sizes[0] / IN_DIM;
    const int n_edges = in_sizes[2];

    // workspace layout
    int*   flag = (int*)d_ws;                      // offset 0
    float* bs   = (float*)d_ws + 16;               // offset 64 B
    float* proj = (float*)d_ws + 64;               // offset 256 B, [N][16] f32

    prep_kernel<<<1, 384, 0, stream>>>(bases, scorer_w, eidx, bs, flag);

    int pblocks = (n_nodes + 255) / 256;
    proj_kernel<<<pblocks, 256, 0, stream>>>(x, attn_w, scorer_w, proj, n_nodes);

    int eblocks = (n_edges + 255) / 256;
    edge_kernel<<<eblocks, 256, 0, stream>>>(eidx, ew, attn_b, scorer_b, proj,
                                             bs, flag, out, n_edges);
}